// Round 5
// baseline (160.759 us; speedup 1.0000x reference)
//
#include <hip/hip_runtime.h>
#include <hip/hip_bf16.h>
#include <math.h>

#define NW 4096
#define NL 32
#define ND 256
#define ND2 512

typedef __attribute__((ext_vector_type(8))) short short8;
typedef __attribute__((ext_vector_type(4))) short short4v;
typedef __attribute__((ext_vector_type(4))) float floatx4;

__device__ inline float bfval(short s) {
  union { unsigned u; float f; } v;
  v.u = ((unsigned)(unsigned short)s) << 16;
  return v.f;
}
__device__ inline short bf16s(float x) {
  __hip_bfloat16 h = __float2bfloat16(x);
  return *reinterpret_cast<short*>(&h);
}

// ---------------------------------------------------------------------------
// ws layout:
//   wT    fp32 [3][256][256]                 (chr conv w, [k][ci][co])
//   part  fp32 [512][64]
//   h     fp32 [1024]
//   Tb    bf16 [4 cotile][3 k][128 c][64 co] (char conv tables)
//   u     bf16 [4098][512]  (guard rows at both ends)
//   Wb    bf16 [3][512 co][512 ci]           (sent conv w)
// ---------------------------------------------------------------------------

// prep: coalesced transposes (lanes = innermost write dim) + guard zero.
// grid 1281: [0,1024) sent w, [1024,1280) chr w, 1280 guards.
__global__ __launch_bounds__(256) void prep_kernel(
    const float* __restrict__ conv_sent_w, const float* __restrict__ conv_chr_w,
    float* __restrict__ wT, short* __restrict__ Wb,
    short* __restrict__ u_base) {
  int b = blockIdx.x;
  int tid = threadIdx.x;
  if (b < 1024) {                // sent w: 262144 (co,ci) pairs, lanes = ci
    int g = b * 256 + tid;
    int co = g >> 9, ci = g & 511;
    const float* s = conv_sent_w + co * 1536 + ci * 3;   // 12B/lane contiguous
    float f0 = s[0], f1 = s[1], f2 = s[2];
    int o = co * 512 + ci;
    Wb[o] = bf16s(f0);                    // k=0 plane, coalesced
    Wb[262144 + o] = bf16s(f1);
    Wb[524288 + o] = bf16s(f2);
  } else if (b < 1280) {         // chr w: 65536 (ci,co) pairs, lanes = co
    int g = (b - 1024) * 256 + tid;
    int ci = g >> 8, co = g & 255;
    const float* s = conv_chr_w + co * 768 + ci * 3;
    float f0 = s[0], f1 = s[1], f2 = s[2];
    int o = ci * 256 + co;
    wT[o] = f0;                           // coalesced 256B/wave
    wT[65536 + o] = f1;
    wT[131072 + o] = f2;
  } else {                       // guard rows (t=-1, t=4096)
    u_base[tid] = 0;
    u_base[tid + 256] = 0;
    u_base[4097 * 512 + tid] = 0;
    u_base[4097 * 512 + tid + 256] = 0;
  }
}

// T tables in bf16, layout [cotile][k][c][64co]
// grid 96: k = b>>5, c0 = (b&31)*4 ; 256 threads = co
__global__ __launch_bounds__(256) void table_kernel(
    const float* __restrict__ chr_emb, const float* __restrict__ wT,
    __hip_bfloat16* __restrict__ Tb) {
  __shared__ float s_e[4][256];
  int k = blockIdx.x >> 5;
  int c0 = (blockIdx.x & 31) * 4;
  int co = threadIdx.x;
#pragma unroll
  for (int j = 0; j < 4; ++j) s_e[j][co] = chr_emb[(c0 + j) * 256 + co];
  __syncthreads();
  const float* wk = wT + k * 65536;
  float a0 = 0.f, a1 = 0.f, a2 = 0.f, a3 = 0.f;
#pragma unroll 8
  for (int ci = 0; ci < 256; ++ci) {
    float w = wk[ci * 256 + co];
    a0 = fmaf(s_e[0][ci], w, a0);
    a1 = fmaf(s_e[1][ci], w, a1);
    a2 = fmaf(s_e[2][ci], w, a2);
    a3 = fmaf(s_e[3][ci], w, a3);
  }
  int base = ((co >> 6) * 3 + k) * 8192 + (co & 63);
  Tb[base + (c0 + 0) * 64] = __float2bfloat16(a0);
  Tb[base + (c0 + 1) * 64] = __float2bfloat16(a1);
  Tb[base + (c0 + 2) * 64] = __float2bfloat16(a2);
  Tb[base + (c0 + 3) * 64] = __float2bfloat16(a3);
}

// char path: LDS-staged bf16 tables read 4-cos-at-a-time via ds_read_b64,
// fused word-emb gather. grid 256: cotile = b>>6, word chunk = (b&63)*64.
__global__ __launch_bounds__(256) void char_word_kernel(
    const int* __restrict__ words, const int* __restrict__ wic,
    const __hip_bfloat16* __restrict__ Tb, const float* __restrict__ word_emb,
    const float* __restrict__ bias, short* __restrict__ u0s) {
  __shared__ short sT[3 * 128 * 64];   // 48 KB
  __shared__ int s_wic[64 * 32];       // 8 KB
  __shared__ int s_wid[64];
  int ct = blockIdx.x >> 6;
  int w0 = (blockIdx.x & 63) * 64;
  int tid = threadIdx.x;
  {
    const uint4* src = (const uint4*)((const short*)Tb + ct * 24576);
    uint4* dst = (uint4*)sT;
#pragma unroll
    for (int i = 0; i < 12; ++i) dst[tid + i * 256] = src[tid + i * 256];
    const int4* wsrc = (const int4*)(wic + w0 * 32);
    int4* wdst = (int4*)s_wic;
    wdst[tid] = wsrc[tid];
    wdst[tid + 256] = wsrc[tid + 256];
    if (tid < 64) s_wid[tid] = words[w0 + tid];
  }
  __syncthreads();
  const int co4 = (tid & 15) * 4;   // 4 consecutive cos per thread
  const int slot = tid >> 4;        // 16 slots x 4 words
  const short* T0 = sT;
  const short* T1 = sT + 8192;
  const short* T2 = sT + 16384;
  const float4 bb = *(const float4*)(bias + ct * 64 + co4);
  for (int wi = 0; wi < 4; ++wi) {
    int wl = slot * 4 + wi;
    // fused word-emb gather (16 lanes x 16B = 256B/word, coalesced)
    {
      float4 we = *(const float4*)(word_emb + s_wid[wl] * ND + ct * 64 + co4);
      short4v ws;
      ws.x = bf16s(we.x); ws.y = bf16s(we.y); ws.z = bf16s(we.z); ws.w = bf16s(we.w);
      *(short4v*)&u0s[(w0 + wl) * ND2 + ct * 64 + co4] = ws;
    }
    // chars into registers (8 x b128 LDS reads)
    int cc[32];
    {
      const int4* cp = (const int4*)(s_wic + wl * 32);
#pragma unroll
      for (int i = 0; i < 8; ++i) {
        int4 v = cp[i];
        cc[i * 4] = v.x; cc[i * 4 + 1] = v.y; cc[i * 4 + 2] = v.z; cc[i * 4 + 3] = v.w;
      }
    }
    float m0 = -INFINITY, m1 = -INFINITY, m2 = -INFINITY, m3 = -INFINITY;
#pragma unroll
    for (int t = 0; t < NL; ++t) {
      short4v q1 = *(const short4v*)&T1[cc[t] * 64 + co4];
      float s0 = bfval(q1.x), s1 = bfval(q1.y), s2 = bfval(q1.z), s3 = bfval(q1.w);
      if (t > 0) {
        short4v q0 = *(const short4v*)&T0[cc[t - 1] * 64 + co4];
        s0 += bfval(q0.x); s1 += bfval(q0.y); s2 += bfval(q0.z); s3 += bfval(q0.w);
      }
      if (t < NL - 1) {
        short4v q2 = *(const short4v*)&T2[cc[t + 1] * 64 + co4];
        s0 += bfval(q2.x); s1 += bfval(q2.y); s2 += bfval(q2.z); s3 += bfval(q2.w);
      }
      m0 = fmaxf(m0, s0); m1 = fmaxf(m1, s1);
      m2 = fmaxf(m2, s2); m3 = fmaxf(m3, s3);
    }
    short4v res;
    res.x = bf16s(m0 + bb.x); res.y = bf16s(m1 + bb.y);
    res.z = bf16s(m2 + bb.z); res.w = bf16s(m3 + bb.w);
    *(short4v*)&u0s[(w0 + wl) * ND2 + ND + ct * 64 + co4] = res;
  }
}

// Sentence conv GEMM (unchanged from R4): C[co][t] = sum Wb[k][co][ci]*u[t+k-1][ci]
// 64co x 64t tile, 512 blocks = 2/CU, XOR-swizzled LDS, simple sync staging.
__global__ __launch_bounds__(256, 2) void sent_conv_mfma(
    const __hip_bfloat16* __restrict__ u0,
    const __hip_bfloat16* __restrict__ Wb,
    float* __restrict__ partial) {
  __shared__ short As[64 * 64];
  __shared__ short Bs[64 * 64];
  __shared__ float sm[4][32];
  const int tid = threadIdx.x;
  const int t0 = blockIdx.x * 64;
  const int co0 = blockIdx.y * 64;
  const int wave = tid >> 6, lane = tid & 63;
  const int wy = wave >> 1, wx = wave & 1;
  const int m = lane & 15, q = lane >> 4;

  floatx4 acc[2][2];
#pragma unroll
  for (int i = 0; i < 2; ++i)
#pragma unroll
    for (int j = 0; j < 2; ++j) acc[i][j] = (floatx4){0.f, 0.f, 0.f, 0.f};

  int aoff[2][2], boff[2][2];
#pragma unroll
  for (int kk = 0; kk < 2; ++kk) {
#pragma unroll
    for (int i = 0; i < 2; ++i) {
      int row = wy * 32 + i * 16 + m;
      aoff[kk][i] = row * 64 + (((kk * 4 + q) ^ (row & 7)) * 8);
      row = wx * 32 + i * 16 + m;
      boff[kk][i] = row * 64 + (((kk * 4 + q) ^ (row & 7)) * 8);
    }
  }

  const int sc = tid & 7, sr = tid >> 3;
  const int swc = (sc ^ (sr & 7)) * 8;
  const short* WbS = (const short*)Wb;
  const short* uS = (const short*)u0;

  for (int s = 0; s < 24; ++s) {
    int k = s >> 3, ci0 = (s & 7) << 6;
    const short* WbK = WbS + k * 262144 + (co0 + sr) * 512 + ci0 + sc * 8;
    const short* uK = uS + (t0 + sr + k - 1) * 512 + ci0 + sc * 8;
    uint4 a0 = *(const uint4*)(WbK);
    uint4 a1 = *(const uint4*)(WbK + 32 * 512);
    uint4 b0 = *(const uint4*)(uK);
    uint4 b1 = *(const uint4*)(uK + 32 * 512);
    *(uint4*)&As[sr * 64 + swc] = a0;
    *(uint4*)&As[(sr + 32) * 64 + swc] = a1;
    *(uint4*)&Bs[sr * 64 + swc] = b0;
    *(uint4*)&Bs[(sr + 32) * 64 + swc] = b1;
    __syncthreads();
#pragma unroll
    for (int kk = 0; kk < 2; ++kk) {
      short8 av0 = *(const short8*)&As[aoff[kk][0]];
      short8 av1 = *(const short8*)&As[aoff[kk][1]];
      short8 bv0 = *(const short8*)&Bs[boff[kk][0]];
      short8 bv1 = *(const short8*)&Bs[boff[kk][1]];
      acc[0][0] = __builtin_amdgcn_mfma_f32_16x16x32_bf16(av0, bv0, acc[0][0], 0, 0, 0);
      acc[0][1] = __builtin_amdgcn_mfma_f32_16x16x32_bf16(av0, bv1, acc[0][1], 0, 0, 0);
      acc[1][0] = __builtin_amdgcn_mfma_f32_16x16x32_bf16(av1, bv0, acc[1][0], 0, 0, 0);
      acc[1][1] = __builtin_amdgcn_mfma_f32_16x16x32_bf16(av1, bv1, acc[1][1], 0, 0, 0);
    }
    __syncthreads();
  }

#pragma unroll
  for (int i = 0; i < 2; ++i)
#pragma unroll
    for (int r = 0; r < 4; ++r) {
      float x = fmaxf(acc[i][0][r], acc[i][1][r]);
#pragma unroll
      for (int off = 1; off < 16; off <<= 1)
        x = fmaxf(x, __shfl_xor(x, off, 64));
      if (m == 0) sm[wave][i * 16 + q * 4 + r] = x;
    }
  __syncthreads();
  if (tid < 64) {
    int whalf = tid >> 5;
    float v = fmaxf(sm[whalf * 2 + 0][tid & 31], sm[whalf * 2 + 1][tid & 31]);
    partial[(co0 + tid) * 64 + blockIdx.x] = v;
  }
}

// fc1 with fused r-reduction. grid 128 x 512 threads (8 waves -> 8 outputs).
__global__ __launch_bounds__(512) void fc1_kernel(
    const float* __restrict__ partial, const float* __restrict__ bs,
    const float* __restrict__ w1, const float* __restrict__ b1,
    float* __restrict__ h) {
  __shared__ float s_r[512];
  int tid = threadIdx.x;
  {
    const float4* p = (const float4*)(partial + tid * 64);
    float mm = -INFINITY;
#pragma unroll
    for (int j = 0; j < 16; ++j) {
      float4 v = p[j];
      mm = fmaxf(mm, fmaxf(fmaxf(v.x, v.y), fmaxf(v.z, v.w)));
    }
    s_r[tid] = mm + bs[tid];
  }
  __syncthreads();
  int wave = tid >> 6, lane = tid & 63;
  int o = blockIdx.x * 8 + wave;
  const float4* wv = (const float4*)(w1 + o * 512 + lane * 8);
  const float4* rv = (const float4*)(s_r + lane * 8);
  float4 w0 = wv[0], w1v = wv[1];
  float4 r0 = rv[0], r1 = rv[1];
  float acc = w0.x * r0.x + w0.y * r0.y + w0.z * r0.z + w0.w * r0.w +
              w1v.x * r1.x + w1v.y * r1.y + w1v.z * r1.z + w1v.w * r1.w;
#pragma unroll
  for (int off = 32; off >= 1; off >>= 1) acc += __shfl_down(acc, off, 64);
  if (lane == 0) h[o] = tanhf(acc + b1[o]);
}

__global__ __launch_bounds__(128) void fc2_kernel(
    const float* __restrict__ h, const float* __restrict__ w2,
    const float* __restrict__ b2, float* __restrict__ out) {
  int tid = threadIdx.x;
  int o = tid >> 6;
  int lane = tid & 63;
  float acc = 0.f;
#pragma unroll
  for (int j = 0; j < 16; ++j)
    acc = fmaf(w2[o * 1024 + lane + j * 64], h[lane + j * 64], acc);
#pragma unroll
  for (int off = 32; off >= 1; off >>= 1) acc += __shfl_down(acc, off, 64);
  if (lane == 0) out[o] = acc + b2[o];
}

extern "C" void kernel_launch(void* const* d_in, const int* in_sizes, int n_in,
                              void* d_out, int out_size, void* d_ws, size_t ws_size,
                              hipStream_t stream) {
  const int*   words       = (const int*)d_in[0];
  const int*   wic         = (const int*)d_in[1];
  const float* word_emb    = (const float*)d_in[2];
  const float* chr_emb     = (const float*)d_in[3];
  const float* conv_chr_w  = (const float*)d_in[4];
  const float* conv_chr_b  = (const float*)d_in[5];
  const float* conv_sent_w = (const float*)d_in[6];
  const float* conv_sent_b = (const float*)d_in[7];
  const float* w1          = (const float*)d_in[8];
  const float* b1          = (const float*)d_in[9];
  const float* w2          = (const float*)d_in[10];
  const float* b2          = (const float*)d_in[11];
  float* out = (float*)d_out;

  float* ws    = (float*)d_ws;
  float* wT    = ws;                        // 196608 f
  float* part  = wT + 196608;               // 32768 f
  float* h_buf = part + 32768;              // 1024 f
  short* Tb    = (short*)(h_buf + 1024);    // 98304 bf16
  short* u_base = Tb + 98304;               // 4098*512 bf16
  short* u0s   = u_base + 512;
  __hip_bfloat16* u0 = (__hip_bfloat16*)u0s;
  short* Wb    = u_base + 4098 * 512;       // 3*512*512 bf16

  prep_kernel<<<1281, 256, 0, stream>>>(conv_sent_w, conv_chr_w, wT, Wb, u_base);
  table_kernel<<<96, 256, 0, stream>>>(chr_emb, wT, (__hip_bfloat16*)Tb);
  char_word_kernel<<<256, 256, 0, stream>>>(words, wic, (const __hip_bfloat16*)Tb,
                                            word_emb, conv_chr_b, u0s);
  sent_conv_mfma<<<dim3(64, 8), 256, 0, stream>>>(u0, (const __hip_bfloat16*)Wb, part);
  fc1_kernel<<<128, 512, 0, stream>>>(part, conv_sent_b, w1, b1, h_buf);
  fc2_kernel<<<1, 128, 0, stream>>>(h_buf, w2, b2, out);
}